// Round 13
// baseline (128.714 us; speedup 1.0000x reference)
//
#include <hip/hip_runtime.h>
#include <hip/hip_bf16.h>
#include <stdint.h>

// Problem constants (fixed by setup_inputs)
#define B_   8
#define S_   2048
#define C_   768
#define HID_ 768
#define H_   12
#define KW   9
#define D_   64
#define M_   (B_ * S_)   // 16384 rows
#define PADW 4           // KW/2
#define HK_  108         // H_*KW
#define NPAD 128         // padded N for the attn projection

typedef __attribute__((ext_vector_type(4))) float  floatx4;
typedef __attribute__((ext_vector_type(8))) __bf16 bf16x8;

#define GLD_LDS16(gptr, lptr)                                                  \
    __builtin_amdgcn_global_load_lds(                                          \
        (__attribute__((address_space(1))) void*)(gptr),                       \
        (__attribute__((address_space(3))) void*)(lptr), 16, 0, 0)

#define BARR() do { __builtin_amdgcn_s_barrier();                              \
                    __builtin_amdgcn_sched_barrier(0); } while (0)
#define LGKM0() do { asm volatile("s_waitcnt lgkmcnt(0)" ::: "memory");        \
                     __builtin_amdgcn_sched_barrier(0); } while (0)

// ---------------------------------------------------------------------------
// Kernel 0: convert pw_weight and attn_W (zero-padded to 128 rows) to bf16.
// Vectorized x4.
// ---------------------------------------------------------------------------
__global__ __launch_bounds__(256) void convert_w_kernel(
    const float* __restrict__ pwW, const float* __restrict__ attnW,
    __hip_bfloat16* __restrict__ pwWb, __hip_bfloat16* __restrict__ attnWb)
{
    int i = blockIdx.x * 256 + threadIdx.x;      // [0, C_*HID_/4)
    {
        const float4 v = *reinterpret_cast<const float4*>(&pwW[(size_t)i * 4]);
        union { __hip_bfloat16 h[4]; uint2 u; } o;
        o.h[0] = __float2bfloat16(v.x);
        o.h[1] = __float2bfloat16(v.y);
        o.h[2] = __float2bfloat16(v.z);
        o.h[3] = __float2bfloat16(v.w);
        *reinterpret_cast<uint2*>(&pwWb[(size_t)i * 4]) = o.u;
    }
    if (i < (NPAD * HID_) / 4) {
        const int base = i * 4;
        const int n = base / HID_;
        union { __hip_bfloat16 h[4]; uint2 u; } o;
#pragma unroll
        for (int e = 0; e < 4; ++e) {
            float v = (n < HK_) ? attnW[base + e] : 0.0f;
            o.h[e] = __float2bfloat16(v);
        }
        *reinterpret_cast<uint2*>(&attnWb[base]) = o.u;
    }
}

// ---------------------------------------------------------------------------
// Kernel 1: depthwise conv1d (K=9, pad 4), sliding-window, TSD=32.
// ---------------------------------------------------------------------------
#define TSD 32

__global__ __launch_bounds__(256) void dwconv_kernel(
    const float* __restrict__ hidden, const float* __restrict__ dw_w,
    __hip_bfloat16* __restrict__ dw_out)
{
    int idx  = blockIdx.x * 256 + threadIdx.x;   // [0, 98304)
    int hq   = idx % (HID_ / 4);                 // 0..191
    int rest = idx / (HID_ / 4);                 // 0..511
    int sc   = rest % (S_ / TSD);                // 0..63
    int b    = rest / (S_ / TSD);                // 0..7
    int h    = hq * 4;
    int s0   = sc * TSD;
    size_t base = (size_t)b * S_ * HID_ + h;

    float w[36];
    const float4* wp = reinterpret_cast<const float4*>(dw_w + (size_t)h * KW);
#pragma unroll
    for (int i = 0; i < 9; ++i) {
        float4 t = wp[i];
        w[4 * i + 0] = t.x; w[4 * i + 1] = t.y;
        w[4 * i + 2] = t.z; w[4 * i + 3] = t.w;
    }

    float4 win[KW];
#pragma unroll
    for (int k = 0; k < 8; ++k) {
        int sp = s0 + k - PADW;
        float4 v = {0.f, 0.f, 0.f, 0.f};
        if ((unsigned)sp < (unsigned)S_)
            v = *reinterpret_cast<const float4*>(&hidden[base + (size_t)sp * HID_]);
        win[k] = v;
    }

#pragma unroll
    for (int i = 0; i < TSD; ++i) {
        int sp = s0 + i + PADW;
        float4 nv = {0.f, 0.f, 0.f, 0.f};
        if ((unsigned)sp < (unsigned)S_)
            nv = *reinterpret_cast<const float4*>(&hidden[base + (size_t)sp * HID_]);
        win[8] = nv;

        float a0 = 0.f, a1 = 0.f, a2 = 0.f, a3 = 0.f;
#pragma unroll
        for (int k = 0; k < KW; ++k) {
            a0 += win[k].x * w[k];
            a1 += win[k].y * w[9 + k];
            a2 += win[k].z * w[18 + k];
            a3 += win[k].w * w[27 + k];
        }
        union { __hip_bfloat16 bv[4]; uint2 u; } o;
        o.bv[0] = __float2bfloat16(a0);
        o.bv[1] = __float2bfloat16(a1);
        o.bv[2] = __float2bfloat16(a2);
        o.bv[3] = __float2bfloat16(a3);
        *reinterpret_cast<uint2*>(&dw_out[base + (size_t)(s0 + i) * HID_]) = o.u;

#pragma unroll
        for (int k = 0; k < 8; ++k) win[k] = win[k + 1];
    }
}

// ---------------------------------------------------------------------------
// FUSED kernel v6 — ZERO-BARRIER K-loop via wave-private staging:
// Block = 32 rows, 256 threads = 4 waves (1r x 4c), wave tile 32x64, BK=32.
// Every wave stages its OWN A copy (2 KB/buf, redundant x4) and its OWN
// B 64-col slice (4 KB/buf) -> no cross-wave LDS deps in the K-loop ->
// no barriers: per wave {stage(kt+1) [6 gload_lds]; vmcnt(6); ds_read; MFMA}.
// Write-after-read safe within a wave (own MFMA lgkm-consumed before next
// stage issue); waves drift freely. Barriers only at nt/P/gemm2 boundaries.
// 64-B LDS rows: swizzle slot ^= (row>>1)&3 -> 2-way conflicts (free).
// 3 n-tiles of 256 cols; per nt: 24-step K-loop, P=(acc1+bias)*query -> bf16
// swizzled LDS; acc2 += P @ attnW-slice. Finale: double softmax -> filt.
// LDS 48 KB: A[wave][buf] 16K @0, B[wave][buf] 32K @16384.
// P (16K) and LG (16.5K) alias the B region. Grid 512 = 2 blocks/CU.
// ---------------------------------------------------------------------------
__global__ __launch_bounds__(256, 2) void fused_gemm_kernel(
    const __hip_bfloat16* __restrict__ A,     // dwb   [M_][HID_]
    const __hip_bfloat16* __restrict__ Bt,    // pwWb  [C_][HID_]
    const __hip_bfloat16* __restrict__ Wt,    // attnWb[NPAD][C_]
    const float* __restrict__ bias,           // sep_b [C_]
    const float* __restrict__ query,          // [M_][C_]
    const float* __restrict__ attn_b,         // [HK_]
    float* __restrict__ filt)                 // [B_][H_][S_][KW]
{
    __shared__ __align__(16) char lds[49152];
    char* Plds = lds + 16384;                 // 16 KB alias of B region
    float* LG  = (float*)(lds + 16384);       // [32][129] f32, alias (later)

    const int t    = threadIdx.x;
    const int lane = t & 63;
    const int wave = t >> 6;       // 0..3  (= col group)
    const int l16  = lane & 15, lq = lane >> 4;

    const int row0 = (int)blockIdx.x * 32;

    char* Aw = lds + wave * 4096;             // 2 bufs x 2 KB (private)
    char* Bw = lds + 16384 + wave * 8192;     // 2 bufs x 4 KB (private)

    // staging lane constants: 1 instr = 1 KB = 16 rows x 64 B
    // row-in-instr = lane>>2, slot = lane&3; source slot = slot^((row>>1)&3)
    // = (lane&3)^((lane>>3)&3)  [since instr strides are 0 mod 4 rows-of-2]
    const int srow  = lane >> 2;                        // 0..15
    const int sslot = (lane & 3) ^ ((lane >> 3) & 3);   // pre-swizzled source
    const __hip_bfloat16* aS =
        A + (size_t)(row0 + srow) * HID_ + sslot * 8;   // + j*16*HID_ + kt*32

    floatx4 acc2[2][2];
#pragma unroll
    for (int m = 0; m < 2; ++m)
#pragma unroll
        for (int n = 0; n < 2; ++n) acc2[m][n] = (floatx4){0.f, 0.f, 0.f, 0.f};

    for (int nt = 0; nt < 3; ++nt) {
        const __hip_bfloat16* bS =
            Bt + (size_t)(nt * 256 + wave * 64 + srow) * HID_ + sslot * 8;

        floatx4 acc1[2][4];
#pragma unroll
        for (int m = 0; m < 2; ++m)
#pragma unroll
            for (int n = 0; n < 4; ++n) acc1[m][n] = (floatx4){0.f, 0.f, 0.f, 0.f};

        // 6 gload_lds per stage: 2 A-instrs (rows 0-15, 16-31), 4 B-instrs
#define STG(kt, buf) do {                                                      \
        GLD_LDS16(aS + (kt) * 32,             Aw + (buf) * 2048);              \
        GLD_LDS16(aS + 16 * HID_ + (kt) * 32, Aw + (buf) * 2048 + 1024);       \
        _Pragma("unroll")                                                      \
        for (int _j = 0; _j < 4; ++_j)                                         \
            GLD_LDS16(bS + (size_t)_j * 16 * HID_ + (kt) * 32,                 \
                      Bw + (buf) * 4096 + _j * 1024);                          \
    } while (0)

        STG(0, 0);
#pragma unroll 2
        for (int kt = 0; kt < 24; ++kt) {
            const int cur = kt & 1;
            if (kt < 23) {
                STG(kt + 1, cur ^ 1);
                asm volatile("s_waitcnt vmcnt(6)" ::: "memory");
            } else {
                asm volatile("s_waitcnt vmcnt(0)" ::: "memory");
            }
            __builtin_amdgcn_sched_barrier(0);

            const char* ab = Aw + cur * 2048;
            const char* bb = Bw + cur * 4096;
            bf16x8 av[2], bv[4];
#pragma unroll
            for (int m = 0; m < 2; ++m) {
                const int r = m * 16 + l16;
                av[m] = *(const bf16x8*)(ab + r * 64 +
                    ((lq ^ ((r >> 1) & 3)) << 4));
            }
#pragma unroll
            for (int n = 0; n < 4; ++n) {
                const int c = n * 16 + l16;
                bv[n] = *(const bf16x8*)(bb + c * 64 +
                    ((lq ^ ((c >> 1) & 3)) << 4));
            }
#pragma unroll
            for (int m = 0; m < 2; ++m)
#pragma unroll
                for (int n = 0; n < 4; ++n)
                    acc1[m][n] = __builtin_amdgcn_mfma_f32_16x16x32_bf16(
                        av[m], bv[n], acc1[m][n], 0, 0, 0);
        }
#undef STG

        // all waves out of the K-loop (no in-flight gload_lds: vmcnt(0) above)
        BARR();

        // epilogue: P = (acc1 + bias) * query -> bf16, XOR-swizzled LDS write
#pragma unroll
        for (int m = 0; m < 2; ++m)
#pragma unroll
            for (int n = 0; n < 4; ++n) {
                const int cl   = wave * 64 + n * 16 + l16;   // 0..255
                const int gcol = nt * 256 + cl;
                const float bvv = bias[gcol];
#pragma unroll
                for (int j = 0; j < 4; ++j) {
                    const int row = m * 16 + lq * 4 + j;     // 0..31
                    float v = (acc1[m][n][j] + bvv) *
                              query[(size_t)(row0 + row) * C_ + gcol];
                    __hip_bfloat16 hb = __float2bfloat16(v);
                    *(uint16_t*)(Plds + row * 512 +
                                 ((cl * 2) ^ ((row & 7) << 4))) =
                        *(uint16_t*)&hb;
                }
            }
        LGKM0();
        BARR();                           // P complete

        // gemm2 pass: acc2 += P[32x256] @ W-slice[128 x 256]^T
#pragma unroll
        for (int kk = 0; kk < 8; ++kk) {
            bf16x8 pv[2], wv[2];
#pragma unroll
            for (int m = 0; m < 2; ++m) {
                const int r = m * 16 + l16;
                pv[m] = *(const bf16x8*)(Plds + r * 512 +
                    ((kk * 64 + lq * 16) ^ ((l16 & 7) << 4)));
            }
#pragma unroll
            for (int n = 0; n < 2; ++n) {
                const int wrow = wave * 32 + n * 16 + l16;   // 0..127
                wv[n] = *(const bf16x8*)(Wt + (size_t)wrow * C_ +
                                         nt * 256 + kk * 32 + lq * 8);
            }
#pragma unroll
            for (int m = 0; m < 2; ++m)
#pragma unroll
                for (int n = 0; n < 2; ++n)
                    acc2[m][n] = __builtin_amdgcn_mfma_f32_16x16x32_bf16(
                        pv[m], wv[n], acc2[m][n], 0, 0, 0);
        }
        LGKM0();
        BARR();                           // P reads done; next nt reuses LDS
    }

    // finale: acc2 -> LG (stride 129), per-(h,row) double softmax ->
    // filt[B][H][S][KW]
#pragma unroll
    for (int m = 0; m < 2; ++m)
#pragma unroll
        for (int n = 0; n < 2; ++n) {
            const int cl = wave * 32 + n * 16 + l16;
#pragma unroll
            for (int j = 0; j < 4; ++j) {
                const int row = m * 16 + lq * 4 + j;
                LG[row * 129 + cl] = acc2[m][n][j];
            }
        }
    LGKM0();
    BARR();

    for (int id = t; id < 32 * H_; id += 256) {
        const int h   = id >> 5;          // 0..11 (h-outer: contiguous writes)
        const int row = id & 31;
        float v[KW];
#pragma unroll
        for (int k = 0; k < KW; ++k)
            v[k] = LG[row * 129 + h * KW + k] + attn_b[h * KW + k];
#pragma unroll
        for (int pass = 0; pass < 2; ++pass) {
            float mx = v[0];
#pragma unroll
            for (int k = 1; k < KW; ++k) mx = fmaxf(mx, v[k]);
            float s = 0.f;
#pragma unroll
            for (int k = 0; k < KW; ++k) { v[k] = __expf(v[k] - mx); s += v[k]; }
            float inv = 1.f / s;
#pragma unroll
            for (int k = 0; k < KW; ++k) v[k] *= inv;
        }
        const int grow = row0 + row;
        const int b    = grow >> 11;      // / S_
        const int s    = grow & (S_ - 1);
        const size_t base = (((size_t)b * H_ + h) * S_ + s) * KW;
#pragma unroll
        for (int k = 0; k < KW; ++k) filt[base + k] = v[k];
    }
}

// ---------------------------------------------------------------------------
// Kernel 5: light conv, sliding-window; filt[B][H][S][KW] contiguous slab.
// ---------------------------------------------------------------------------
#define TSL 16
#define SCHK 256   // s per block (16 s-groups x TSL)

__global__ __launch_bounds__(256) void lightconv_kernel(
    const float* __restrict__ value, const float* __restrict__ filt,
    float* __restrict__ out)
{
    __shared__ __align__(16) float fl[SCHK * KW];   // 2304 floats

    const int tid = threadIdx.x;
    const int blk = blockIdx.x;                   // [0, 768)
    const int nSC = S_ / SCHK;                    // 8
    const int b   = blk / (H_ * nSC);
    const int rem = blk % (H_ * nSC);
    const int h   = rem / nSC;
    const int sch = rem % nSC;
    const int S0  = sch * SCHK;

    {
        const float4* src = reinterpret_cast<const float4*>(
            filt + (((size_t)b * H_ + h) * S_ + S0) * KW);
        float4* dst = reinterpret_cast<float4*>(fl);
        for (int j = tid; j < (SCHK * KW) / 4; j += 256)   // 576 float4
            dst[j] = src[j];
    }
    __syncthreads();

    const int d4 = tid & 15;
    const int sg = tid >> 4;                      // 0..15
    const int s0 = S0 + sg * TSL;
    const size_t vbase = (size_t)b * S_ * C_ + h * D_ + d4 * 4;
    const float* flrow = &fl[(sg * TSL) * KW];

    float4 win[KW];
#pragma unroll
    for (int k = 0; k < 8; ++k) {
        int sp = s0 + k - PADW;
        float4 v = {0.f, 0.f, 0.f, 0.f};
        if ((unsigned)sp < (unsigned)S_)
            v = *reinterpret_cast<const float4*>(&value[vbase + (size_t)sp * C_]);
        win[k] = v;
    }

#pragma unroll
    for (int i = 0; i < TSL; ++i) {
        int sp = s0 + i + PADW;
        float4 nv = {0.f, 0.f, 0.f, 0.f};
        if ((unsigned)sp < (unsigned)S_)
            nv = *reinterpret_cast<const float4*>(&value[vbase + (size_t)sp * C_]);
        win[8] = nv;

        float4 acc = {0.f, 0.f, 0.f, 0.f};
#pragma unroll
        for (int k = 0; k < KW; ++k) {
            float f = flrow[i * KW + k];
            acc.x += win[k].x * f;
            acc.y += win[k].y * f;
            acc.z += win[k].z * f;
            acc.w += win[k].w * f;
        }
        *reinterpret_cast<float4*>(&out[vbase + (size_t)(s0 + i) * C_]) = acc;

#pragma unroll
        for (int k = 0; k < 8; ++k) win[k] = win[k + 1];
    }
}

// ---------------------------------------------------------------------------
extern "C" void kernel_launch(void* const* d_in, const int* in_sizes, int n_in,
                              void* d_out, int out_size, void* d_ws, size_t ws_size,
                              hipStream_t stream)
{
    const float* query  = (const float*)d_in[0];
    const float* value  = (const float*)d_in[1];
    const float* hidden = (const float*)d_in[2];
    const float* dw_w   = (const float*)d_in[3];
    const float* pw_w   = (const float*)d_in[4];
    const float* sep_b  = (const float*)d_in[5];
    const float* attn_W = (const float*)d_in[6];
    const float* attn_b = (const float*)d_in[7];
    float* out = (float*)d_out;

    // workspace layout (all regions fully rewritten every call)
    char* ws = (char*)d_ws;
    __hip_bfloat16* dwb    = (__hip_bfloat16*)(ws);              // 25,165,824 B
    __hip_bfloat16* pwWb   = (__hip_bfloat16*)(ws + 25165824);   //  1,179,648 B
    __hip_bfloat16* attnWb = (__hip_bfloat16*)(ws + 26345472);   //    196,608 B
    float*          filt   = (float*)(ws + 26542080);            //  7,077,888 B
    // total: 33,619,968 B

    convert_w_kernel<<<(C_ * HID_) / (256 * 4), 256, 0, stream>>>(
        pw_w, attn_W, pwWb, attnWb);

    dwconv_kernel<<<(M_ * (HID_ / 4)) / (256 * TSD), 256, 0, stream>>>(hidden, dw_w, dwb);

    fused_gemm_kernel<<<M_ / 32, 256, 0, stream>>>(
        dwb, pwWb, attnWb, sep_b, query, attn_b, filt);

    lightconv_kernel<<<B_ * H_ * (S_ / SCHK), 256, 0, stream>>>(value, filt, out);
}

// Round 15
// 94.720 us; speedup vs baseline: 1.3589x; 1.3589x over previous
//
#include <hip/hip_runtime.h>
#include <hip/hip_bf16.h>
#include <stdint.h>

// Problem constants (fixed by setup_inputs)
#define B_   8
#define S_   2048
#define C_   768
#define HID_ 768
#define H_   12
#define KW   9
#define D_   64
#define M_   (B_ * S_)   // 16384 rows
#define PADW 4           // KW/2
#define HK_  108         // H_*KW
#define NPAD 128         // padded N for the attn projection

typedef __attribute__((ext_vector_type(4))) float  floatx4;
typedef __attribute__((ext_vector_type(8))) __bf16 bf16x8;

#define GLD_LDS16(gptr, lptr)                                                  \
    __builtin_amdgcn_global_load_lds(                                          \
        (__attribute__((address_space(1))) void*)(gptr),                       \
        (__attribute__((address_space(3))) void*)(lptr), 16, 0, 0)

#define BARR() do { __builtin_amdgcn_s_barrier();                              \
                    __builtin_amdgcn_sched_barrier(0); } while (0)
#define LGKM0() do { asm volatile("s_waitcnt lgkmcnt(0)" ::: "memory");        \
                     __builtin_amdgcn_sched_barrier(0); } while (0)

// ---------------------------------------------------------------------------
// Kernel 0: convert pw_weight and attn_W (zero-padded to 128 rows) to bf16.
// Vectorized x4: one thread = 4 consecutive elements (float4 -> 4x bf16).
// ---------------------------------------------------------------------------
__global__ __launch_bounds__(256) void convert_w_kernel(
    const float* __restrict__ pwW, const float* __restrict__ attnW,
    __hip_bfloat16* __restrict__ pwWb, __hip_bfloat16* __restrict__ attnWb)
{
    int i = blockIdx.x * 256 + threadIdx.x;      // [0, C_*HID_/4)
    {
        const float4 v = *reinterpret_cast<const float4*>(&pwW[(size_t)i * 4]);
        union { __hip_bfloat16 h[4]; uint2 u; } o;
        o.h[0] = __float2bfloat16(v.x);
        o.h[1] = __float2bfloat16(v.y);
        o.h[2] = __float2bfloat16(v.z);
        o.h[3] = __float2bfloat16(v.w);
        *reinterpret_cast<uint2*>(&pwWb[(size_t)i * 4]) = o.u;
    }
    if (i < (NPAD * HID_) / 4) {
        const int base = i * 4;
        const int n = base / HID_;               // all 4 elems share the row
        union { __hip_bfloat16 h[4]; uint2 u; } o;
#pragma unroll
        for (int e = 0; e < 4; ++e) {
            float v = (n < HK_) ? attnW[base + e] : 0.0f;
            o.h[e] = __float2bfloat16(v);
        }
        *reinterpret_cast<uint2*>(&attnWb[base]) = o.u;
    }
}

// ---------------------------------------------------------------------------
// Kernel 1: depthwise conv1d (K=9, pad 4), sliding-window version.
// TSD=32: window reload overlap 1.25x (40 loads per 32 outputs).
// ---------------------------------------------------------------------------
#define TSD 32

__global__ __launch_bounds__(256) void dwconv_kernel(
    const float* __restrict__ hidden, const float* __restrict__ dw_w,
    __hip_bfloat16* __restrict__ dw_out)
{
    int idx  = blockIdx.x * 256 + threadIdx.x;   // [0, 98304)
    int hq   = idx % (HID_ / 4);                 // 0..191
    int rest = idx / (HID_ / 4);                 // 0..511
    int sc   = rest % (S_ / TSD);                // 0..63
    int b    = rest / (S_ / TSD);                // 0..7
    int h    = hq * 4;
    int s0   = sc * TSD;
    size_t base = (size_t)b * S_ * HID_ + h;     // row-0 addr for this (b, h)

    float w[36];
    const float4* wp = reinterpret_cast<const float4*>(dw_w + (size_t)h * KW);
#pragma unroll
    for (int i = 0; i < 9; ++i) {
        float4 t = wp[i];
        w[4 * i + 0] = t.x; w[4 * i + 1] = t.y;
        w[4 * i + 2] = t.z; w[4 * i + 3] = t.w;
    }

    float4 win[KW];
#pragma unroll
    for (int k = 0; k < 8; ++k) {
        int sp = s0 + k - PADW;
        float4 v = {0.f, 0.f, 0.f, 0.f};
        if ((unsigned)sp < (unsigned)S_)
            v = *reinterpret_cast<const float4*>(&hidden[base + (size_t)sp * HID_]);
        win[k] = v;
    }

#pragma unroll
    for (int i = 0; i < TSD; ++i) {
        int sp = s0 + i + PADW;
        float4 nv = {0.f, 0.f, 0.f, 0.f};
        if ((unsigned)sp < (unsigned)S_)
            nv = *reinterpret_cast<const float4*>(&hidden[base + (size_t)sp * HID_]);
        win[8] = nv;

        float a0 = 0.f, a1 = 0.f, a2 = 0.f, a3 = 0.f;
#pragma unroll
        for (int k = 0; k < KW; ++k) {
            a0 += win[k].x * w[k];
            a1 += win[k].y * w[9 + k];
            a2 += win[k].z * w[18 + k];
            a3 += win[k].w * w[27 + k];
        }
        union { __hip_bfloat16 bv[4]; uint2 u; } o;
        o.bv[0] = __float2bfloat16(a0);
        o.bv[1] = __float2bfloat16(a1);
        o.bv[2] = __float2bfloat16(a2);
        o.bv[3] = __float2bfloat16(a3);
        *reinterpret_cast<uint2*>(&dw_out[base + (size_t)(s0 + i) * HID_]) = o.u;

#pragma unroll
        for (int k = 0; k < 8; ++k) win[k] = win[k + 1];
    }
}

// ---------------------------------------------------------------------------
// FUSED kernel (r7/r9/r12-proven, session best): block = 32 rows,
// 256 threads = 4 waves (1r x 4c), wave tile 32x64 (0.75 ds_read/MFMA).
// 3 n-tiles of 256 cols; per n-tile a 12-step BK=64 double-buffered K-loop
// (counted vmcnt(9)); A and B staged via global_load_lds, XOR-swizzled
// (pre-swizzled global source + XOR'd ds_read, rule 21).
// After each n-tile: P = (acc1+bias)*query -> bf16 -> swizzled LDS;
// acc2 += P @ attnW-slice (W direct from global, L2-hot).
// Finale: acc2 -> LG (stride 129, conflict-free) -> per-(h,row) double
// softmax -> filt in [B][H][S][KW] layout (contiguous for lightconv).
// LDS 72 KB: A-dbuf 2x4K @0, B-dbuf 2x32K @8192.
// P (16 KB) aliases B-buf0; LG (16.1 KB) aliases B-buf1. Grid 512 = 2/CU.
// ---------------------------------------------------------------------------
__global__ __launch_bounds__(256, 2) void fused_gemm_kernel(
    const __hip_bfloat16* __restrict__ A,     // dwb   [M_][HID_]
    const __hip_bfloat16* __restrict__ Bt,    // pwWb  [C_][HID_]
    const __hip_bfloat16* __restrict__ Wt,    // attnWb[NPAD][C_]
    const float* __restrict__ bias,           // sep_b [C_]
    const float* __restrict__ query,          // [M_][C_]
    const float* __restrict__ attn_b,         // [HK_]
    float* __restrict__ filt)                 // [B_][H_][S_][KW]
{
    __shared__ __align__(16) char lds[73728];
    char* Plds = lds + 8192;                  // aliases B-buf0 (16 KB used)
    float* LG  = (float*)(lds + 8192 + 32768);// aliases B-buf1: [32][129] f32

    const int t    = threadIdx.x;
    const int lane = t & 63;
    const int wave = t >> 6;       // 0..3  (= col group wc)
    const int l16  = lane & 15, lq = lane >> 4;

    const int row0 = (int)blockIdx.x * 32;

    // staging constants: 1 instr = 1 KB = 8 rows of 128 B
    const int sr8     = lane >> 3;                      // 0..7
    const int srcslot = (lane & 7) ^ sr8;               // pre-swizzled source
    // A: 4 KB/step, 1 instr per wave (rows wave*8 + sr8)
    const __hip_bfloat16* aS = A + (size_t)(row0 + wave * 8 + sr8) * HID_ + srcslot * 8;

    floatx4 acc2[2][2];
#pragma unroll
    for (int m = 0; m < 2; ++m)
#pragma unroll
        for (int n = 0; n < 2; ++n) acc2[m][n] = (floatx4){0.f, 0.f, 0.f, 0.f};

    for (int nt = 0; nt < 3; ++nt) {
        // B: 32 KB/step, 8 instrs per wave (rows wave*64 + i*8 + sr8)
        const __hip_bfloat16* bS =
            Bt + (size_t)(nt * 256 + wave * 64 + sr8) * HID_ + srcslot * 8;

        floatx4 acc1[2][4];
#pragma unroll
        for (int m = 0; m < 2; ++m)
#pragma unroll
            for (int n = 0; n < 4; ++n) acc1[m][n] = (floatx4){0.f, 0.f, 0.f, 0.f};

#define FSTG(kt, buf) do {                                                     \
        GLD_LDS16(aS + (kt) * 64, lds + (buf) * 4096 + wave * 1024);           \
        _Pragma("unroll")                                                      \
        for (int _i = 0; _i < 8; ++_i)                                         \
            GLD_LDS16(bS + (size_t)_i * 8 * HID_ + (kt) * 64,                  \
                      lds + 8192 + (buf) * 32768 + wave * 8192 + _i * 1024);   \
    } while (0)

        FSTG(0, 0);
#pragma unroll 2
        for (int kt = 0; kt < 12; ++kt) {
            const int cur = kt & 1;
            if (kt < 11) {
                FSTG(kt + 1, cur ^ 1);
                asm volatile("s_waitcnt vmcnt(9)" ::: "memory");
            } else {
                asm volatile("s_waitcnt vmcnt(0)" ::: "memory");
            }
            __builtin_amdgcn_sched_barrier(0);
            BARR();                       // stage(kt) visible to all waves

            const char* ab = lds + cur * 4096;
            const char* bb = lds + 8192 + cur * 32768;
            bf16x8 av[2][2], bv[4][2];
#pragma unroll
            for (int m = 0; m < 2; ++m) {
                const int r = m * 16 + l16;
#pragma unroll
                for (int ks = 0; ks < 2; ++ks)
                    av[m][ks] = *(const bf16x8*)(ab + r * 128 +
                        ((ks * 64 + lq * 16) ^ ((l16 & 7) << 4)));
            }
#pragma unroll
            for (int n = 0; n < 4; ++n) {
                const int r = wave * 64 + n * 16 + l16;
#pragma unroll
                for (int ks = 0; ks < 2; ++ks)
                    bv[n][ks] = *(const bf16x8*)(bb + r * 128 +
                        ((ks * 64 + lq * 16) ^ ((l16 & 7) << 4)));
            }
            __builtin_amdgcn_s_setprio(1);
#pragma unroll
            for (int m = 0; m < 2; ++m)
#pragma unroll
                for (int n = 0; n < 4; ++n)
#pragma unroll
                    for (int ks = 0; ks < 2; ++ks)
                        acc1[m][n] = __builtin_amdgcn_mfma_f32_16x16x32_bf16(
                            av[m][ks], bv[n][ks], acc1[m][n], 0, 0, 0);
            __builtin_amdgcn_s_setprio(0);
            LGKM0();                      // reads drained before overwrite
            BARR();
        }
#undef FSTG

        // epilogue: P = (acc1 + bias) * query -> bf16, XOR-swizzled LDS write
        // (P aliases B-buf0; all buf reads drained at loop exit)
#pragma unroll
        for (int m = 0; m < 2; ++m)
#pragma unroll
            for (int n = 0; n < 4; ++n) {
                const int cl   = wave * 64 + n * 16 + l16;   // 0..255
                const int gcol = nt * 256 + cl;
                const float bvv = bias[gcol];
#pragma unroll
                for (int j = 0; j < 4; ++j) {
                    const int row = m * 16 + lq * 4 + j;     // 0..31
                    float v = (acc1[m][n][j] + bvv) *
                              query[(size_t)(row0 + row) * C_ + gcol];
                    __hip_bfloat16 hb = __float2bfloat16(v);
                    *(uint16_t*)(Plds + row * 512 +
                                 ((cl * 2) ^ ((row & 7) << 4))) =
                        *(uint16_t*)&hb;
                }
            }
        LGKM0();
        BARR();                           // P complete

        // gemm2 pass: acc2 += P[32x256] @ W-slice[128 x 256]^T
#pragma unroll
        for (int kk = 0; kk < 8; ++kk) {
            bf16x8 pv[2], wv[2];
#pragma unroll
            for (int m = 0; m < 2; ++m) {
                const int r = m * 16 + l16;
                pv[m] = *(const bf16x8*)(Plds + r * 512 +
                    ((kk * 64 + lq * 16) ^ ((l16 & 7) << 4)));
            }
#pragma unroll
            for (int n = 0; n < 2; ++n) {
                const int wrow = wave * 32 + n * 16 + l16;   // 0..127
                wv[n] = *(const bf16x8*)(Wt + (size_t)wrow * C_ +
                                         nt * 256 + kk * 32 + lq * 8);
            }
#pragma unroll
            for (int m = 0; m < 2; ++m)
#pragma unroll
                for (int n = 0; n < 2; ++n)
                    acc2[m][n] = __builtin_amdgcn_mfma_f32_16x16x32_bf16(
                        pv[m], wv[n], acc2[m][n], 0, 0, 0);
        }
        LGKM0();
        BARR();                           // P reads done; next nt may overwrite
    }

    // finale: acc2 -> LG (stride 129: h-outer reads hit 32 distinct banks),
    // then per-(h,row) double softmax -> filt[B][H][S][KW]
#pragma unroll
    for (int m = 0; m < 2; ++m)
#pragma unroll
        for (int n = 0; n < 2; ++n) {
            const int cl = wave * 32 + n * 16 + l16;
#pragma unroll
            for (int j = 0; j < 4; ++j) {
                const int row = m * 16 + lq * 4 + j;
                LG[row * 129 + cl] = acc2[m][n][j];
            }
        }
    LGKM0();
    BARR();

    for (int id = t; id < 32 * H_; id += 256) {
        const int h   = id >> 5;          // 0..11 (h-outer: contiguous writes)
        const int row = id & 31;
        float v[KW];
#pragma unroll
        for (int k = 0; k < KW; ++k)
            v[k] = LG[row * 129 + h * KW + k] + attn_b[h * KW + k];
#pragma unroll
        for (int pass = 0; pass < 2; ++pass) {
            float mx = v[0];
#pragma unroll
            for (int k = 1; k < KW; ++k) mx = fmaxf(mx, v[k]);
            float s = 0.f;
#pragma unroll
            for (int k = 0; k < KW; ++k) { v[k] = __expf(v[k] - mx); s += v[k]; }
            float inv = 1.f / s;
#pragma unroll
            for (int k = 0; k < KW; ++k) v[k] *= inv;
        }
        const int grow = row0 + row;
        const int b    = grow >> 11;      // / S_
        const int s    = grow & (S_ - 1);
        const size_t base = (((size_t)b * H_ + h) * S_ + s) * KW;
#pragma unroll
        for (int k = 0; k < KW; ++k) filt[base + k] = v[k];
    }
}

// ---------------------------------------------------------------------------
// Kernel 5: light conv, sliding-window; filt[B][H][S][KW] contiguous slab.
// ---------------------------------------------------------------------------
#define TSL 16
#define SCHK 256   // s per block (16 s-groups x TSL)

__global__ __launch_bounds__(256) void lightconv_kernel(
    const float* __restrict__ value, const float* __restrict__ filt,
    float* __restrict__ out)
{
    __shared__ __align__(16) float fl[SCHK * KW];   // 2304 floats

    const int tid = threadIdx.x;
    const int blk = blockIdx.x;                   // [0, 768)
    const int nSC = S_ / SCHK;                    // 8
    const int b   = blk / (H_ * nSC);
    const int rem = blk % (H_ * nSC);
    const int h   = rem / nSC;
    const int sch = rem % nSC;
    const int S0  = sch * SCHK;

    {
        const float4* src = reinterpret_cast<const float4*>(
            filt + (((size_t)b * H_ + h) * S_ + S0) * KW);
        float4* dst = reinterpret_cast<float4*>(fl);
        for (int j = tid; j < (SCHK * KW) / 4; j += 256)   // 576 float4
            dst[j] = src[j];
    }
    __syncthreads();

    const int d4 = tid & 15;
    const int sg = tid >> 4;                      // 0..15
    const int s0 = S0 + sg * TSL;
    const size_t vbase = (size_t)b * S_ * C_ + h * D_ + d4 * 4;
    const float* flrow = &fl[(sg * TSL) * KW];

    float4 win[KW];
#pragma unroll
    for (int k = 0; k < 8; ++k) {
        int sp = s0 + k - PADW;
        float4 v = {0.f, 0.f, 0.f, 0.f};
        if ((unsigned)sp < (unsigned)S_)
            v = *reinterpret_cast<const float4*>(&value[vbase + (size_t)sp * C_]);
        win[k] = v;
    }

#pragma unroll
    for (int i = 0; i < TSL; ++i) {
        int sp = s0 + i + PADW;
        float4 nv = {0.f, 0.f, 0.f, 0.f};
        if ((unsigned)sp < (unsigned)S_)
            nv = *reinterpret_cast<const float4*>(&value[vbase + (size_t)sp * C_]);
        win[8] = nv;

        float4 acc = {0.f, 0.f, 0.f, 0.f};
#pragma unroll
        for (int k = 0; k < KW; ++k) {
            float f = flrow[i * KW + k];
            acc.x += win[k].x * f;
            acc.y += win[k].y * f;
            acc.z += win[k].z * f;
            acc.w += win[k].w * f;
        }
        *reinterpret_cast<float4*>(&out[vbase + (size_t)(s0 + i) * C_]) = acc;

#pragma unroll
        for (int k = 0; k < 8; ++k) win[k] = win[k + 1];
    }
}

// ---------------------------------------------------------------------------
extern "C" void kernel_launch(void* const* d_in, const int* in_sizes, int n_in,
                              void* d_out, int out_size, void* d_ws, size_t ws_size,
                              hipStream_t stream)
{
    const float* query  = (const float*)d_in[0];
    const float* value  = (const float*)d_in[1];
    const float* hidden = (const float*)d_in[2];
    const float* dw_w   = (const float*)d_in[3];
    const float* pw_w   = (const float*)d_in[4];
    const float* sep_b  = (const float*)d_in[5];
    const float* attn_W = (const float*)d_in[6];
    const float* attn_b = (const float*)d_in[7];
    float* out = (float*)d_out;

    // workspace layout (all regions fully rewritten every call)
    char* ws = (char*)d_ws;
    __hip_bfloat16* dwb    = (__hip_bfloat16*)(ws);              // 25,165,824 B
    __hip_bfloat16* pwWb   = (__hip_bfloat16*)(ws + 25165824);   //  1,179,648 B
    __hip_bfloat16* attnWb = (__hip_bfloat16*)(ws + 26345472);   //    196,608 B
    float*          filt   = (float*)(ws + 26542080);            //  7,077,888 B
    // total: 33,619,968 B

    convert_w_kernel<<<(C_ * HID_) / (256 * 4), 256, 0, stream>>>(
        pw_w, attn_W, pwWb, attnWb);

    dwconv_kernel<<<(M_ * (HID_ / 4)) / (256 * TSD), 256, 0, stream>>>(hidden, dw_w, dwb);

    fused_gemm_kernel<<<M_ / 32, 256, 0, stream>>>(
        dwb, pwWb, attnWb, sep_b, query, attn_b, filt);

    lightconv_kernel<<<B_ * H_ * (S_ / SCHK), 256, 0, stream>>>(value, filt, out);
}